// Round 20
// baseline (327.503 us; speedup 1.0000x reference)
//
#include <hip/hip_runtime.h>

#define DEVINL __device__ __forceinline__

typedef __attribute__((ext_vector_type(8)))  __bf16         bf16x8;
typedef __attribute__((ext_vector_type(4)))  float          f32x4;
typedef __attribute__((ext_vector_type(16))) float          f32x16;
typedef __attribute__((ext_vector_type(8)))  unsigned short ushort8;
typedef __attribute__((ext_vector_type(4)))  unsigned short ushort4v;
typedef __attribute__((ext_vector_type(4)))  unsigned int   uint4v;
typedef __attribute__((ext_vector_type(4)))  float          float4v;

DEVINL unsigned short f2bf(float f) {
  unsigned int u = __float_as_uint(f);
  u += 0x7fffu + ((u >> 16) & 1u);   // round-to-nearest-even
  return (unsigned short)(u >> 16);
}

DEVINL float bf2f(unsigned short u) {
  return __uint_as_float(((unsigned int)u) << 16);
}

DEVINL bf16x8 ldbf8(const unsigned short* p) {
  return __builtin_bit_cast(bf16x8, *(const ushort8*)p);
}

DEVINL unsigned cvtpk_bf16(float lo, float hi) {  // dst.lo16=bf16(lo), dst.hi16=bf16(hi)
  unsigned r;
  asm("v_cvt_pk_bf16_f32 %0, %1, %2" : "=v"(r) : "v"(lo), "v"(hi));
  return r;
}

// async global->LDS, 16B per lane; LDS dest = wave-uniform base + lane*16
DEVINL void gload_lds16(const unsigned short* g, unsigned short* l) {
  __builtin_amdgcn_global_load_lds((const __attribute__((address_space(1))) void*)g,
                                   (__attribute__((address_space(3))) void*)l, 16, 0, 0);
}

// ---------------- fused pre-pass: cvt(x) + transpose(w_qkv) + transpose(w_out) ----
__global__ __launch_bounds__(256) void prepass_kernel(
    const float* __restrict__ x, const float* __restrict__ w_qkv,
    const float* __restrict__ w_out, unsigned short* __restrict__ xb,
    unsigned short* __restrict__ wqkvT, unsigned short* __restrict__ woutT) {
  __shared__ float tile[32][33];
  const int B = blockIdx.x;
  if (B < 1024) {
    const int n4 = 1048576;  // 4096*1024/4
    for (int i = B * 256 + threadIdx.x; i < n4; i += 1024 * 256) {
      float4v v = *(const float4v*)(x + (size_t)4 * i);
      ushort4v o;
      o[0] = f2bf(v[0]); o[1] = f2bf(v[1]); o[2] = f2bf(v[2]); o[3] = f2bf(v[3]);
      *(ushort4v*)(xb + (size_t)4 * i) = o;
    }
    return;
  }
  const float* in; unsigned short* out; int C, bx, by;
  if (B < 4096) { const int idx = B - 1024; bx = idx % 96; by = idx / 96; in = w_qkv; out = wqkvT; C = 3072; }
  else          { const int idx = B - 4096; bx = idx & 31; by = idx >> 5; in = w_out; out = woutT; C = 1024; }
  const int R = 1024;
  const int tx = threadIdx.x & 31, ty = threadIdx.x >> 5;
  const int r0 = by << 5, c0 = bx << 5;
#pragma unroll
  for (int i = 0; i < 32; i += 8)
    tile[ty + i][tx] = in[(size_t)(r0 + ty + i) * C + (c0 + tx)];
  __syncthreads();
#pragma unroll
  for (int i = 0; i < 32; i += 8)
    out[(size_t)(c0 + ty + i) * R + (r0 + tx)] = f2bf(tile[tx][ty + i]);
}

// ---------------- bf16 GEMM: C = A(MxK) * Bt(NxK)^T (128x128 tile) ----------------
// BK=32, 4 waves (2x2). Dbuf LDS via global_load_lds + counted vmcnt(4) + raw
// barriers. Deep granule XOR swizzle kk(row)=(row&3)^((row>>2)&3); reads fold to
// the per-lane constant g^(q&3)^(q>>2). For QKV, column blocks >= 2048 (V third)
// are written in V^T layout via a coalesced LDS relayout.
template <bool OUT_BF16>
__global__ __launch_bounds__(256, 3) void gemm_bt_kernel(
    const unsigned short* __restrict__ A,   // M x K, lda
    const unsigned short* __restrict__ Bt,  // N x K, ldb
    void* __restrict__ Cout,                // M x N, ldc (cols < 2048 if VtOut)
    int M, int N, int K, int lda, int ldb, int ldc,
    unsigned short* __restrict__ VtOut) {   // optional V^T output
  __shared__ __align__(16) unsigned short smem[2][2][128 * 32];  // As=smem[0], Bs=smem[1]
  unsigned short (*As)[128 * 32] = smem[0];
  unsigned short (*Bs)[128 * 32] = smem[1];
  const int tid = threadIdx.x;
  const int lane = tid & 63, wave = tid >> 6;
  const int wr = wave >> 1, wc = wave & 1;
  const int g = lane >> 4, q = lane & 15;
  const int row0 = blockIdx.x << 7, col0 = blockIdx.y << 7;

  const int srow = tid >> 2;
  const int sg = ((tid & 3) ^ (srow & 3) ^ ((srow >> 2) & 3)) << 3;  // pre-swizzled granule
  const unsigned short* Ap0 = A + (size_t)(row0 + srow) * lda + sg;
  const unsigned short* Ap1 = Ap0 + (size_t)64 * lda;
  const unsigned short* Bp0 = Bt + (size_t)(col0 + srow) * ldb + sg;
  const unsigned short* Bp1 = Bp0 + (size_t)64 * ldb;

  f32x4 acc[4][4] = {};

  gload_lds16(Ap0, &As[0][wave * 512]);
  gload_lds16(Ap1, &As[0][2048 + wave * 512]);
  gload_lds16(Bp0, &Bs[0][wave * 512]);
  gload_lds16(Bp1, &Bs[0][2048 + wave * 512]);

  const int gx = (g ^ (q & 3) ^ (q >> 2)) << 3;  // read-side key (per-lane constant)
  const int nk = K >> 5;
  int cur = 0;

  for (int t = 0; t < nk; ++t) {
    if (t + 1 < nk) {
      Ap0 += 32; Ap1 += 32; Bp0 += 32; Bp1 += 32;
      gload_lds16(Ap0, &As[cur ^ 1][wave * 512]);
      gload_lds16(Ap1, &As[cur ^ 1][2048 + wave * 512]);
      gload_lds16(Bp0, &Bs[cur ^ 1][wave * 512]);
      gload_lds16(Bp1, &Bs[cur ^ 1][2048 + wave * 512]);
      asm volatile("s_waitcnt vmcnt(4)" ::: "memory");
    } else {
      asm volatile("s_waitcnt vmcnt(0)" ::: "memory");
    }
    __builtin_amdgcn_s_barrier();

    bf16x8 af[4], bfr[4];
#pragma unroll
    for (int mb = 0; mb < 4; ++mb)
      af[mb] = ldbf8(&As[cur][(wr * 64 + mb * 16 + q) * 32] + gx);
#pragma unroll
    for (int nb = 0; nb < 4; ++nb)
      bfr[nb] = ldbf8(&Bs[cur][(wc * 64 + nb * 16 + q) * 32] + gx);
#pragma unroll
    for (int mb = 0; mb < 4; ++mb)
#pragma unroll
      for (int nb = 0; nb < 4; ++nb)
        acc[mb][nb] = __builtin_amdgcn_mfma_f32_16x16x32_bf16(af[mb], bfr[nb], acc[mb][nb], 0, 0, 0);

    __builtin_amdgcn_s_barrier();
    cur ^= 1;
  }

  const bool isV = OUT_BF16 && (VtOut != nullptr) && (col0 >= 2048);
  if (isV) {
    // coalesced V^T epilogue: relayout through LDS (staging bufs dead after loop)
    unsigned short* T = &smem[0][0][0];  // 128 d x 128 s bf16 = 32KB
    __syncthreads();
#pragma unroll
    for (int mb = 0; mb < 4; ++mb)
#pragma unroll
      for (int nb = 0; nb < 4; ++nb)
#pragma unroll
        for (int r = 0; r < 4; ++r) {
          const int sr = wr * 64 + mb * 16 + g * 4 + r;   // s within tile
          const int dc = wc * 64 + nb * 16 + q;           // d within tile (2 heads)
          T[dc * 128 + sr] = f2bf(acc[mb][nb][r]);
        }
    __syncthreads();
    const int d = tid >> 1, sh = (tid & 1) << 6;
    const int hI = ((col0 - 2048) >> 6) + (d >> 6), dI = d & 63;
    unsigned short* dst = VtOut + ((size_t)((row0 >> 11) * 16 + hI) * 64 + dI) * 2048 +
                          (row0 & 2047) + sh;
    const unsigned short* src = T + d * 128 + sh;
#pragma unroll
    for (int j = 0; j < 8; ++j)
      *(ushort8*)(dst + j * 8) = *(const ushort8*)(src + j * 8);
    return;
  }
#pragma unroll
  for (int mb = 0; mb < 4; ++mb)
#pragma unroll
    for (int nb = 0; nb < 4; ++nb)
#pragma unroll
      for (int r = 0; r < 4; ++r) {
        const int row = row0 + wr * 64 + mb * 16 + g * 4 + r;  // C/D: row=(l>>4)*4+reg
        const int col = col0 + wc * 64 + nb * 16 + q;          //       col=l&15
        const float v = acc[mb][nb][r];
        if (OUT_BF16) ((unsigned short*)Cout)[(size_t)row * ldc + col] = f2bf(v);
        else          ((float*)Cout)[(size_t)row * ldc + col] = v;
      }
}

// ---------------- bf16 GEMM, 64x128 tile (fp32 out) -----------------------------
// Out-projection: grid (64,8) = 512 blocks = 2 blocks/CU. Same dbuf + counted
// vmcnt(3) protocol; deep granule swizzle as above.
__global__ __launch_bounds__(256, 3) void gemm_bt64_kernel(
    const unsigned short* __restrict__ A,   // M x K, lda
    const unsigned short* __restrict__ Bt,  // N x K, ldb
    float* __restrict__ Cout,               // M x N, ldc
    int K, int lda, int ldb, int ldc) {
  __shared__ __align__(16) unsigned short As[2][64 * 32];    // 4KB per buf
  __shared__ __align__(16) unsigned short Bs[2][128 * 32];   // 8KB per buf
  const int tid = threadIdx.x;
  const int lane = tid & 63, wave = tid >> 6;
  const int wr = wave >> 1, wc = wave & 1;
  const int g = lane >> 4, q = lane & 15;
  const int row0 = blockIdx.x << 6, col0 = blockIdx.y << 7;

  const int srow = tid >> 2;
  const int sg = ((tid & 3) ^ (srow & 3) ^ ((srow >> 2) & 3)) << 3;
  const unsigned short* Ap = A + (size_t)(row0 + srow) * lda + sg;   // rows 0..63
  const unsigned short* Bp0 = Bt + (size_t)(col0 + srow) * ldb + sg;
  const unsigned short* Bp1 = Bp0 + (size_t)64 * ldb;

  f32x4 acc[2][4] = {};

  gload_lds16(Ap, &As[0][wave * 512]);
  gload_lds16(Bp0, &Bs[0][wave * 512]);
  gload_lds16(Bp1, &Bs[0][2048 + wave * 512]);

  const int gx = (g ^ (q & 3) ^ (q >> 2)) << 3;
  const int nk = K >> 5;
  int cur = 0;

  for (int t = 0; t < nk; ++t) {
    if (t + 1 < nk) {
      Ap += 32; Bp0 += 32; Bp1 += 32;
      gload_lds16(Ap, &As[cur ^ 1][wave * 512]);
      gload_lds16(Bp0, &Bs[cur ^ 1][wave * 512]);
      gload_lds16(Bp1, &Bs[cur ^ 1][2048 + wave * 512]);
      asm volatile("s_waitcnt vmcnt(3)" ::: "memory");
    } else {
      asm volatile("s_waitcnt vmcnt(0)" ::: "memory");
    }
    __builtin_amdgcn_s_barrier();

    bf16x8 af[2], bfr[4];
#pragma unroll
    for (int mb = 0; mb < 2; ++mb)
      af[mb] = ldbf8(&As[cur][(wr * 32 + mb * 16 + q) * 32] + gx);
#pragma unroll
    for (int nb = 0; nb < 4; ++nb)
      bfr[nb] = ldbf8(&Bs[cur][(wc * 64 + nb * 16 + q) * 32] + gx);
#pragma unroll
    for (int mb = 0; mb < 2; ++mb)
#pragma unroll
      for (int nb = 0; nb < 4; ++nb)
        acc[mb][nb] = __builtin_amdgcn_mfma_f32_16x16x32_bf16(af[mb], bfr[nb], acc[mb][nb], 0, 0, 0);

    __builtin_amdgcn_s_barrier();
    cur ^= 1;
  }

#pragma unroll
  for (int mb = 0; mb < 2; ++mb)
#pragma unroll
    for (int nb = 0; nb < 4; ++nb)
#pragma unroll
      for (int r = 0; r < 4; ++r) {
        const int row = row0 + wr * 32 + mb * 16 + g * 4 + r;
        const int col = col0 + wc * 64 + nb * 16 + q;
        Cout[(size_t)row * ldc + col] = acc[mb][nb][r];
      }
}

// ---------------- causal flash attention (KV split + fused atomic merge tail) ----
// Grid 1024 x 256 thr (4 waves). Block (qc, half): half 0 -> KV tiles [0,qc+1),
// half 1 -> [qc+1, 2qc+2), same 128 q-rows. Round-robin balanced-pair decode.
// After writing its normalized partial + stats, each block releases (threadfence)
// and bumps a device-scope counter for its (bh,qc) pair; the SECOND block to
// arrive acquires and merges the pair's 128x64 slice into Ob (split-K pattern:
// no spin-waits, deterministic, ~26KB per merge, overlaps the attn tail).
__global__ __launch_bounds__(256, 2) void attn_kernel(
    const unsigned short* __restrict__ qkv,  // (B*S) x 2048 row-major: Q|K
    const unsigned short* __restrict__ VtG,  // (B*16*64) x S : V transposed
    unsigned short* __restrict__ OlP,        // (B*S) x H bf16 partial (low) = Ob
    unsigned short* __restrict__ OhP,        // (B*S) x H bf16 partial (high)
    float* __restrict__ stats,               // [bh*2048+s][4] = ml,ll,mh,lh
    unsigned int* __restrict__ ctr) {        // 512 pair counters (zeroed per launch)
  const int S = 2048, H = 1024, LD = 2048;
  const int tid = threadIdx.x;
  const int wave = tid >> 6, lane = tid & 63;
  const int c = lane & 31, hh = lane >> 5;

  // balanced decode: CU gets L, L+256, L+512, L+768 -> {(p,h0),(p,h1),(15-p,h0),(15-p,h1)}
  const int L = blockIdx.x;
  const int group = L >> 8, r0_ = L & 255;
  const int pairid = r0_ & 7, bh = r0_ >> 3;
  const int qc = (group & 2) ? (15 - pairid) : pairid;
  const int half = group & 1;
  const int b = bh >> 4, h = bh & 15;
  const int q0w = qc * 128 + wave * 32;        // this wave's 32 q-rows

  const unsigned short* Qb = qkv + (size_t)b * S * LD + h * 64;
  const unsigned short* Kb = Qb + 1024;
  const unsigned short* Vt = VtG + (size_t)(b * 16 + h) * 64 * S;

  __shared__ __align__(16) unsigned short Ks[2][64 * 64];   // [kv][d], swizzled
  __shared__ __align__(16) unsigned short Vs[2][64 * 64];   // [d][kv], swizzled

  const int srow = lane >> 3;                        // 0..7
  const int srcg = ((lane & 7) ^ srow) << 3;         // pre-swizzled granule (shorts)
  const int wrow = wave * 8 + srow;                  // 0..31

  const int nit = qc + 1;          // KV tiles this block processes
  const int tb = half ? nit : 0;   // tile index base for this half

  // prologue: stage tile tb into buffer 0 (issued before Q loads)
  {
    const int cc = tb << 6;
    gload_lds16(Kb + (size_t)(cc + wrow) * LD + srcg,      Ks[0] + wave * 512);
    gload_lds16(Kb + (size_t)(cc + 32 + wrow) * LD + srcg, Ks[0] + 2048 + wave * 512);
    gload_lds16(Vt + (size_t)wrow * S + cc + srcg,         Vs[0] + wave * 512);
    gload_lds16(Vt + (size_t)(32 + wrow) * S + cc + srcg,  Vs[0] + 2048 + wave * 512);
  }

  // Q fragments: lane holds Q[q0w+c][kc*16 + hh*8 + 0..7]
  bf16x8 qf[4];
#pragma unroll
  for (int kc = 0; kc < 4; ++kc)
    qf[kc] = ldbf8(Qb + (size_t)(q0w + c) * LD + kc * 16 + hh * 8);

  f32x16 acc[2] = {};            // O^T: row d = db*32+(r&3)+8(r>>2)+4hh, col = q0w+c
  float m_r = -1e30f, l_r = 0.f; // m uniform across hh pair; l per-lane partial
  const float CE = 0.125f * 1.44269504f;  // 1/sqrt(dh) * log2(e)

  int cur = 0;
  const int swz = (c & 7) << 3;  // read-side XOR (shorts)

  for (int t = 0; t < nit; ++t) {
    if (t + 1 < nit) {           // issue next tile's loads; stay in flight
      const int c1 = (tb + t + 1) << 6;
      unsigned short* KsN = Ks[cur ^ 1];
      unsigned short* VsN = Vs[cur ^ 1];
      gload_lds16(Kb + (size_t)(c1 + wrow) * LD + srcg,      KsN + wave * 512);
      gload_lds16(Kb + (size_t)(c1 + 32 + wrow) * LD + srcg, KsN + 2048 + wave * 512);
      gload_lds16(Vt + (size_t)wrow * S + c1 + srcg,         VsN + wave * 512);
      gload_lds16(Vt + (size_t)(32 + wrow) * S + c1 + srcg,  VsN + 2048 + wave * 512);
      asm volatile("s_waitcnt vmcnt(4)" ::: "memory");   // tile t resident
    } else {
      asm volatile("s_waitcnt vmcnt(0)" ::: "memory");
    }
    __builtin_amdgcn_s_barrier();  // all waves' stage(t) visible

    const int c0 = (tb + t) << 6;
    const unsigned short* KsC = Ks[cur];
    const unsigned short* VsC = Vs[cur];

    if (c0 <= q0w + 31) {  // wave has unmasked rows in this tile
      int nv = ((q0w + 31 - c0) >> 5) + 1; if (nv > 2) nv = 2;  // valid 32-kv chunks

      // K fragments: A-operand rows kv = n*32+c, k = kc*16+hh*8
      bf16x8 kf[2][4];
#pragma unroll
      for (int n = 0; n < 2; ++n) if (n < nv)
#pragma unroll
        for (int kc = 0; kc < 4; ++kc)
          kf[n][kc] = ldbf8(KsC + (n * 32 + c) * 64 + ((kc * 16 + hh * 8) ^ swz));

      // S^T = K Q^T : st[n] rows kv, cols qrow
      f32x16 st[2] = {};
      __builtin_amdgcn_s_setprio(1);
#pragma unroll
      for (int n = 0; n < 2; ++n) if (n < nv)
#pragma unroll
        for (int kc = 0; kc < 4; ++kc)
          st[n] = __builtin_amdgcn_mfma_f32_32x32x16_bf16(kf[n][kc], qf[kc], st[n], 0, 0, 0);
      __builtin_amdgcn_s_setprio(0);

      // V fragments early (latency hides under softmax): rows d = db*32+c
      bf16x8 vf[2][4];
#pragma unroll
      for (int db = 0; db < 2; ++db)
#pragma unroll
        for (int kk = 0; kk < 4; ++kk) if (kk < 2 * nv)
          vf[db][kk] = ldbf8(VsC + (db * 32 + c) * 64 + ((kk * 16 + hh * 8) ^ swz));

      if (c0 + 63 > q0w) {  // causal mask (diag region only)
#pragma unroll
        for (int n = 0; n < 2; ++n) if (n < nv)
#pragma unroll
          for (int r = 0; r < 16; ++r) {
            const int kv = c0 + n * 32 + (r & 3) + 8 * (r >> 2) + 4 * hh;
            if (kv > q0w + c) st[n][r] = -1e30f;
          }
      }

      // defer-max online softmax; 4-partial trees break serial VALU chains
      f32x4 pm = {-1e30f, -1e30f, -1e30f, -1e30f};
#pragma unroll
      for (int n = 0; n < 2; ++n) if (n < nv)
#pragma unroll
        for (int r = 0; r < 16; ++r) pm[r & 3] = fmaxf(pm[r & 3], st[n][r]);
      const float pmax = fmaxf(fmaxf(pm[0], pm[1]), fmaxf(pm[2], pm[3]));
      if (!__all(pmax <= m_r + 64.f)) {   // rare: update running max, rescale
        float px = fmaxf(pmax, __shfl_xor(pmax, 32));
        const float mn = fmaxf(m_r, px);
        const float sf = __builtin_amdgcn_exp2f((m_r - mn) * CE);
        m_r = mn; l_r *= sf;
#pragma unroll
        for (int db = 0; db < 2; ++db) acc[db] *= sf;
      }
      const float mC = m_r * CE;
      f32x4 la = {0.f, 0.f, 0.f, 0.f};
#pragma unroll
      for (int n = 0; n < 2; ++n) if (n < nv)
#pragma unroll
        for (int r = 0; r < 16; ++r) {
          const float p = __builtin_amdgcn_exp2f(fmaf(st[n][r], CE, -mC));
          st[n][r] = p;
          la[r & 3] += p;
        }
      l_r += (la[0] + la[1]) + (la[2] + la[3]);

      // P relayout in-register: cvt_pk pairs then permlane32_swap
      bf16x8 pa[4];
#pragma unroll
      for (int n = 0; n < 2; ++n) if (n < nv) {
        unsigned T0 = cvtpk_bf16(st[n][0],  st[n][1]);
        unsigned T1 = cvtpk_bf16(st[n][2],  st[n][3]);
        unsigned T2 = cvtpk_bf16(st[n][4],  st[n][5]);
        unsigned T3 = cvtpk_bf16(st[n][6],  st[n][7]);
        unsigned T4 = cvtpk_bf16(st[n][8],  st[n][9]);
        unsigned T5 = cvtpk_bf16(st[n][10], st[n][11]);
        unsigned T6 = cvtpk_bf16(st[n][12], st[n][13]);
        unsigned T7 = cvtpk_bf16(st[n][14], st[n][15]);
        asm("v_permlane32_swap_b32 %0, %1" : "+v"(T0), "+v"(T2));
        asm("v_permlane32_swap_b32 %0, %1" : "+v"(T1), "+v"(T3));
        asm("v_permlane32_swap_b32 %0, %1" : "+v"(T4), "+v"(T6));
        asm("v_permlane32_swap_b32 %0, %1" : "+v"(T5), "+v"(T7));
        uint4v w0; w0[0] = T0; w0[1] = T1; w0[2] = T2; w0[3] = T3;
        uint4v w1; w1[0] = T4; w1[1] = T5; w1[2] = T6; w1[3] = T7;
        pa[2 * n]     = __builtin_bit_cast(bf16x8, w0);
        pa[2 * n + 1] = __builtin_bit_cast(bf16x8, w1);
      }

      // O^T += V^T P
      __builtin_amdgcn_s_setprio(1);
#pragma unroll
      for (int kk = 0; kk < 4; ++kk) if (kk < 2 * nv)
#pragma unroll
        for (int db = 0; db < 2; ++db)
          acc[db] = __builtin_amdgcn_mfma_f32_32x32x16_bf16(vf[db][kk], pa[kk], acc[db], 0, 0, 0);
      __builtin_amdgcn_s_setprio(0);
    }

    __builtin_amdgcn_s_barrier();  // all waves done reading buf[cur]
    cur ^= 1;
  }

  // epilogue: store normalized bf16 partial (avg) + per-row stats
  const float lt = l_r + __shfl_xor(l_r, 32);
  const float inv = lt > 0.f ? 1.f / lt : 0.f;   // guard fully-masked high waves
  unsigned short* Op = half ? OhP : OlP;
  const size_t rowbase = (size_t)(b * S + q0w + c) * H + h * 64;
#pragma unroll
  for (int db = 0; db < 2; ++db)
#pragma unroll
    for (int blk = 0; blk < 4; ++blk) {
      ushort4v o;
#pragma unroll
      for (int j = 0; j < 4; ++j) o[j] = f2bf(acc[db][blk * 4 + j] * inv);
      *(ushort4v*)(Op + rowbase + db * 32 + blk * 8 + hh * 4) = o;
    }
  if (hh == 0) {
    float* sp = stats + ((((size_t)(b * 16 + h)) << 11) + q0w + c) * 4 + (half ? 2 : 0);
    sp[0] = m_r; sp[1] = lt;
  }

  // ---- fused merge tail: second-arriving block of the (bh,qc) pair merges ----
  __threadfence();                       // release partial + stats (agent scope)
  __shared__ int sOld;
  if (tid == 0) sOld = (int)atomicAdd(&ctr[(bh << 4) + qc], 1u);
  __syncthreads();
  if (sOld == 1) {
    __threadfence();                     // acquire: invalidate stale L1/L2 lines
    const int row = tid >> 1;            // 0..127
    const int col0m = (tid & 1) << 5;    // 0 or 32
    const int sRow = qc * 128 + row;
    const float* sp = stats + ((((size_t)bh) << 11) + sRow) * 4;
    const float ml = sp[0], ll = sp[1], mh_ = sp[2], lh_ = sp[3];
    const float mn = fmaxf(ml, mh_);
    const float a_ = ll * __builtin_amdgcn_exp2f((ml - mn) * CE);
    const float b_ = lh_ * __builtin_amdgcn_exp2f((mh_ - mn) * CE);
    const float iv = 1.f / (a_ + b_);
    const float wl = a_ * iv, wh_ = b_ * iv;
    const size_t base = (size_t)(b * S + sRow) * H + h * 64 + col0m;
#pragma unroll
    for (int j = 0; j < 4; ++j) {
      const ushort8 lo = *(const ushort8*)(OlP + base + j * 8);
      const ushort8 hi = *(const ushort8*)(OhP + base + j * 8);
      ushort8 o;
#pragma unroll
      for (int e = 0; e < 8; ++e) o[e] = f2bf(wl * bf2f(lo[e]) + wh_ * bf2f(hi[e]));
      *(ushort8*)(OlP + base + j * 8) = o;
    }
  }
}

extern "C" void kernel_launch(void* const* d_in, const int* in_sizes, int n_in,
                              void* d_out, int out_size, void* d_ws, size_t ws_size,
                              hipStream_t stream) {
  const float* x     = (const float*)d_in[0];
  const float* w_qkv = (const float*)d_in[1];
  const float* w_out = (const float*)d_in[2];
  const int B = 2, S = 2048, H = 1024;
  const int M = B * S;  // 4096

  // workspace layout (ushort elements), total 48 MB:
  unsigned short* xb    = (unsigned short*)d_ws;        // M*H    (8 MB) -> OhP after QKV
  unsigned short* wqkvT = xb + (size_t)M * H;           // 3H*H   (6 MB) -> stats after QKV
  unsigned short* woutT = wqkvT + (size_t)3 * H * H;    // H*H    (2 MB)
  unsigned short* qkb   = woutT + (size_t)H * H;        // M*2048 (16 MB) : Q|K
  unsigned short* VtG   = qkb + (size_t)M * 2048;       // B*16*64*S (8 MB)
  unsigned short* Ob    = VtG + (size_t)B * 16 * 64 * S;// M*H    (8 MB) : low partial
  unsigned short* OhP   = xb;                           // reuse (exactly M*H)
  float*          stats = (float*)wqkvT;                // 1 MB of the 6 MB region
  unsigned int*   ctr   = (unsigned int*)d_out;         // 2KB; overwritten by out-GEMM

  // zero the pair counters (graph-capturable async memset)
  hipMemsetAsync(ctr, 0, 512 * sizeof(unsigned int), stream);

  // fused pre-pass: cvt(x) + transpose(w_qkv) + transpose(w_out)
  prepass_kernel<<<5120, 256, 0, stream>>>(x, w_qkv, w_out, xb, wqkvT, woutT);

  // qkv = x @ w_qkv; Q|K -> qkb (ldc=2048), V third -> VtG in (b,h,d,s) layout
  gemm_bt_kernel<true><<<dim3(M / 128, (3 * H) / 128), 256, 0, stream>>>(
      xb, wqkvT, qkb, M, 3 * H, H, H, H, 2048, VtG);

  // causal multi-head attention + fused pair merge (1024 balanced blocks)
  attn_kernel<<<1024, 256, 0, stream>>>(qkb, VtG, Ob, OhP, stats, ctr);

  // out = attn @ w_out (fp32 out, 64x128 tiles -> 512 blocks = 2 blocks/CU)
  gemm_bt64_kernel<<<dim3(M / 64, H / 128), 256, 0, stream>>>(
      Ob, woutT, (float*)d_out, H, H, H, H);
}

// Round 21
// 114.465 us; speedup vs baseline: 2.8612x; 2.8612x over previous
//
#include <hip/hip_runtime.h>

#define DEVINL __device__ __forceinline__

typedef __attribute__((ext_vector_type(8)))  __bf16         bf16x8;
typedef __attribute__((ext_vector_type(4)))  float          f32x4;
typedef __attribute__((ext_vector_type(16))) float          f32x16;
typedef __attribute__((ext_vector_type(8)))  unsigned short ushort8;
typedef __attribute__((ext_vector_type(4)))  unsigned short ushort4v;
typedef __attribute__((ext_vector_type(4)))  unsigned int   uint4v;
typedef __attribute__((ext_vector_type(4)))  float          float4v;

DEVINL unsigned short f2bf(float f) {
  unsigned int u = __float_as_uint(f);
  u += 0x7fffu + ((u >> 16) & 1u);   // round-to-nearest-even
  return (unsigned short)(u >> 16);
}

DEVINL float bf2f(unsigned short u) {
  return __uint_as_float(((unsigned int)u) << 16);
}

DEVINL bf16x8 ldbf8(const unsigned short* p) {
  return __builtin_bit_cast(bf16x8, *(const ushort8*)p);
}

DEVINL unsigned cvtpk_bf16(float lo, float hi) {  // dst.lo16=bf16(lo), dst.hi16=bf16(hi)
  unsigned r;
  asm("v_cvt_pk_bf16_f32 %0, %1, %2" : "=v"(r) : "v"(lo), "v"(hi));
  return r;
}

// async global->LDS, 16B per lane; LDS dest = wave-uniform base + lane*16
DEVINL void gload_lds16(const unsigned short* g, unsigned short* l) {
  __builtin_amdgcn_global_load_lds((const __attribute__((address_space(1))) void*)g,
                                   (__attribute__((address_space(3))) void*)l, 16, 0, 0);
}

// ---------------- fused pre-pass: cvt(x) + transpose(w_qkv) + transpose(w_out) ----
__global__ __launch_bounds__(256) void prepass_kernel(
    const float* __restrict__ x, const float* __restrict__ w_qkv,
    const float* __restrict__ w_out, unsigned short* __restrict__ xb,
    unsigned short* __restrict__ wqkvT, unsigned short* __restrict__ woutT) {
  __shared__ float tile[32][33];
  const int B = blockIdx.x;
  if (B < 1024) {
    const int n4 = 1048576;  // 4096*1024/4
    for (int i = B * 256 + threadIdx.x; i < n4; i += 1024 * 256) {
      float4v v = *(const float4v*)(x + (size_t)4 * i);
      ushort4v o;
      o[0] = f2bf(v[0]); o[1] = f2bf(v[1]); o[2] = f2bf(v[2]); o[3] = f2bf(v[3]);
      *(ushort4v*)(xb + (size_t)4 * i) = o;
    }
    return;
  }
  const float* in; unsigned short* out; int C, bx, by;
  if (B < 4096) { const int idx = B - 1024; bx = idx % 96; by = idx / 96; in = w_qkv; out = wqkvT; C = 3072; }
  else          { const int idx = B - 4096; bx = idx & 31; by = idx >> 5; in = w_out; out = woutT; C = 1024; }
  const int R = 1024;
  const int tx = threadIdx.x & 31, ty = threadIdx.x >> 5;
  const int r0 = by << 5, c0 = bx << 5;
#pragma unroll
  for (int i = 0; i < 32; i += 8)
    tile[ty + i][tx] = in[(size_t)(r0 + ty + i) * C + (c0 + tx)];
  __syncthreads();
#pragma unroll
  for (int i = 0; i < 32; i += 8)
    out[(size_t)(c0 + ty + i) * R + (r0 + tx)] = f2bf(tile[tx][ty + i]);
}

// ---------------- bf16 GEMM: C = A(MxK) * Bt(NxK)^T (128x128 tile) ----------------
// BK=32, 4 waves (2x2). Dbuf LDS via global_load_lds + counted vmcnt(4) + raw
// barriers. Deep granule XOR swizzle kk(row)=(row&3)^((row>>2)&3): reads fold to
// the per-lane constant g^(q&3)^(q>>2) -> residual conflicts 4-way -> 2-way(free).
// For QKV, column blocks >= 2048 (the V third) are written in V^T layout via a
// coalesced LDS relayout (reusing the staging buffers after the final barrier).
template <bool OUT_BF16>
__global__ __launch_bounds__(256, 3) void gemm_bt_kernel(
    const unsigned short* __restrict__ A,   // M x K, lda
    const unsigned short* __restrict__ Bt,  // N x K, ldb
    void* __restrict__ Cout,                // M x N, ldc (cols < 2048 if VtOut)
    int M, int N, int K, int lda, int ldb, int ldc,
    unsigned short* __restrict__ VtOut) {   // optional V^T output
  __shared__ __align__(16) unsigned short smem[2][2][128 * 32];  // As=smem[0], Bs=smem[1]
  unsigned short (*As)[128 * 32] = smem[0];
  unsigned short (*Bs)[128 * 32] = smem[1];
  const int tid = threadIdx.x;
  const int lane = tid & 63, wave = tid >> 6;
  const int wr = wave >> 1, wc = wave & 1;
  const int g = lane >> 4, q = lane & 15;
  const int row0 = blockIdx.x << 7, col0 = blockIdx.y << 7;

  const int srow = tid >> 2;
  const int sg = ((tid & 3) ^ (srow & 3) ^ ((srow >> 2) & 3)) << 3;  // pre-swizzled granule
  const unsigned short* Ap0 = A + (size_t)(row0 + srow) * lda + sg;
  const unsigned short* Ap1 = Ap0 + (size_t)64 * lda;
  const unsigned short* Bp0 = Bt + (size_t)(col0 + srow) * ldb + sg;
  const unsigned short* Bp1 = Bp0 + (size_t)64 * ldb;

  f32x4 acc[4][4] = {};

  gload_lds16(Ap0, &As[0][wave * 512]);
  gload_lds16(Ap1, &As[0][2048 + wave * 512]);
  gload_lds16(Bp0, &Bs[0][wave * 512]);
  gload_lds16(Bp1, &Bs[0][2048 + wave * 512]);

  const int gx = (g ^ (q & 3) ^ (q >> 2)) << 3;  // read-side key (per-lane constant)
  const int nk = K >> 5;
  int cur = 0;

  for (int t = 0; t < nk; ++t) {
    if (t + 1 < nk) {
      Ap0 += 32; Ap1 += 32; Bp0 += 32; Bp1 += 32;
      gload_lds16(Ap0, &As[cur ^ 1][wave * 512]);
      gload_lds16(Ap1, &As[cur ^ 1][2048 + wave * 512]);
      gload_lds16(Bp0, &Bs[cur ^ 1][wave * 512]);
      gload_lds16(Bp1, &Bs[cur ^ 1][2048 + wave * 512]);
      asm volatile("s_waitcnt vmcnt(4)" ::: "memory");
    } else {
      asm volatile("s_waitcnt vmcnt(0)" ::: "memory");
    }
    __builtin_amdgcn_s_barrier();

    bf16x8 af[4], bfr[4];
#pragma unroll
    for (int mb = 0; mb < 4; ++mb)
      af[mb] = ldbf8(&As[cur][(wr * 64 + mb * 16 + q) * 32] + gx);
#pragma unroll
    for (int nb = 0; nb < 4; ++nb)
      bfr[nb] = ldbf8(&Bs[cur][(wc * 64 + nb * 16 + q) * 32] + gx);
#pragma unroll
    for (int mb = 0; mb < 4; ++mb)
#pragma unroll
      for (int nb = 0; nb < 4; ++nb)
        acc[mb][nb] = __builtin_amdgcn_mfma_f32_16x16x32_bf16(af[mb], bfr[nb], acc[mb][nb], 0, 0, 0);

    __builtin_amdgcn_s_barrier();
    cur ^= 1;
  }

  const bool isV = OUT_BF16 && (VtOut != nullptr) && (col0 >= 2048);
  if (isV) {
    // coalesced V^T epilogue: relayout through LDS (staging bufs dead after loop)
    unsigned short* T = &smem[0][0][0];  // 128 d x 128 s bf16 = 32KB
    __syncthreads();
#pragma unroll
    for (int mb = 0; mb < 4; ++mb)
#pragma unroll
      for (int nb = 0; nb < 4; ++nb)
#pragma unroll
        for (int r = 0; r < 4; ++r) {
          const int sr = wr * 64 + mb * 16 + g * 4 + r;   // s within tile
          const int dc = wc * 64 + nb * 16 + q;           // d within tile (2 heads)
          T[dc * 128 + sr] = f2bf(acc[mb][nb][r]);
        }
    __syncthreads();
    const int d = tid >> 1, sh = (tid & 1) << 6;
    const int hI = ((col0 - 2048) >> 6) + (d >> 6), dI = d & 63;
    unsigned short* dst = VtOut + ((size_t)((row0 >> 11) * 16 + hI) * 64 + dI) * 2048 +
                          (row0 & 2047) + sh;
    const unsigned short* src = T + d * 128 + sh;
#pragma unroll
    for (int j = 0; j < 8; ++j)
      *(ushort8*)(dst + j * 8) = *(const ushort8*)(src + j * 8);
    return;
  }
#pragma unroll
  for (int mb = 0; mb < 4; ++mb)
#pragma unroll
    for (int nb = 0; nb < 4; ++nb)
#pragma unroll
      for (int r = 0; r < 4; ++r) {
        const int row = row0 + wr * 64 + mb * 16 + g * 4 + r;  // C/D: row=(l>>4)*4+reg
        const int col = col0 + wc * 64 + nb * 16 + q;          //       col=l&15
        const float v = acc[mb][nb][r];
        if (OUT_BF16) ((unsigned short*)Cout)[(size_t)row * ldc + col] = f2bf(v);
        else          ((float*)Cout)[(size_t)row * ldc + col] = v;
      }
}

// ---------------- bf16 GEMM, 64x128 tile (fp32 out) -----------------------------
// Out-projection: grid (64,8) = 512 blocks = 2 blocks/CU. Same dbuf + counted
// vmcnt(3) protocol; deep granule swizzle as above.
__global__ __launch_bounds__(256, 3) void gemm_bt64_kernel(
    const unsigned short* __restrict__ A,   // M x K, lda
    const unsigned short* __restrict__ Bt,  // N x K, ldb
    float* __restrict__ Cout,               // M x N, ldc
    int K, int lda, int ldb, int ldc) {
  __shared__ __align__(16) unsigned short As[2][64 * 32];    // 4KB per buf
  __shared__ __align__(16) unsigned short Bs[2][128 * 32];   // 8KB per buf
  const int tid = threadIdx.x;
  const int lane = tid & 63, wave = tid >> 6;
  const int wr = wave >> 1, wc = wave & 1;
  const int g = lane >> 4, q = lane & 15;
  const int row0 = blockIdx.x << 6, col0 = blockIdx.y << 7;

  const int srow = tid >> 2;
  const int sg = ((tid & 3) ^ (srow & 3) ^ ((srow >> 2) & 3)) << 3;
  const unsigned short* Ap = A + (size_t)(row0 + srow) * lda + sg;   // rows 0..63
  const unsigned short* Bp0 = Bt + (size_t)(col0 + srow) * ldb + sg;
  const unsigned short* Bp1 = Bp0 + (size_t)64 * ldb;

  f32x4 acc[2][4] = {};

  gload_lds16(Ap, &As[0][wave * 512]);
  gload_lds16(Bp0, &Bs[0][wave * 512]);
  gload_lds16(Bp1, &Bs[0][2048 + wave * 512]);

  const int gx = (g ^ (q & 3) ^ (q >> 2)) << 3;
  const int nk = K >> 5;
  int cur = 0;

  for (int t = 0; t < nk; ++t) {
    if (t + 1 < nk) {
      Ap += 32; Bp0 += 32; Bp1 += 32;
      gload_lds16(Ap, &As[cur ^ 1][wave * 512]);
      gload_lds16(Bp0, &Bs[cur ^ 1][wave * 512]);
      gload_lds16(Bp1, &Bs[cur ^ 1][2048 + wave * 512]);
      asm volatile("s_waitcnt vmcnt(3)" ::: "memory");
    } else {
      asm volatile("s_waitcnt vmcnt(0)" ::: "memory");
    }
    __builtin_amdgcn_s_barrier();

    bf16x8 af[2], bfr[4];
#pragma unroll
    for (int mb = 0; mb < 2; ++mb)
      af[mb] = ldbf8(&As[cur][(wr * 32 + mb * 16 + q) * 32] + gx);
#pragma unroll
    for (int nb = 0; nb < 4; ++nb)
      bfr[nb] = ldbf8(&Bs[cur][(wc * 64 + nb * 16 + q) * 32] + gx);
#pragma unroll
    for (int mb = 0; mb < 2; ++mb)
#pragma unroll
      for (int nb = 0; nb < 4; ++nb)
        acc[mb][nb] = __builtin_amdgcn_mfma_f32_16x16x32_bf16(af[mb], bfr[nb], acc[mb][nb], 0, 0, 0);

    __builtin_amdgcn_s_barrier();
    cur ^= 1;
  }

#pragma unroll
  for (int mb = 0; mb < 2; ++mb)
#pragma unroll
    for (int nb = 0; nb < 4; ++nb)
#pragma unroll
      for (int r = 0; r < 4; ++r) {
        const int row = row0 + wr * 32 + mb * 16 + g * 4 + r;
        const int col = col0 + wc * 64 + nb * 16 + q;
        Cout[(size_t)row * ldc + col] = acc[mb][nb][r];
      }
}

// ---------------- causal flash attention (cross-block KV split) ----------------
// Grid 1024 x 256 thr (4 waves). Block (qc, half): half 0 -> KV tiles [0,qc+1),
// half 1 -> [qc+1, 2qc+2), same 128 q-rows. 1024 blocks = 4 blocks/CU = 4
// waves/SIMD. Round-robin balanced-pair decode (R17: XCD-affine cuts FETCH
// 72->12MB but is ~2us slower -> not L2-fill-bound). (256,2) bound ON PURPOSE.
// R20 lesson: per-block device-scope threadfence merge tail = 5.5x regression;
// the separate BW-bound merge kernel is the right design on non-coherent XCDs.
__global__ __launch_bounds__(256, 2) void attn_kernel(
    const unsigned short* __restrict__ qkv,  // (B*S) x 2048 row-major: Q|K
    const unsigned short* __restrict__ VtG,  // (B*16*64) x S : V transposed
    unsigned short* __restrict__ OlP,        // (B*S) x H bf16 partial (low)
    unsigned short* __restrict__ OhP,        // (B*S) x H bf16 partial (high)
    float* __restrict__ stats) {             // [bh*2048+s][4] = ml,ll,mh,lh
  const int S = 2048, H = 1024, LD = 2048;
  const int tid = threadIdx.x;
  const int wave = tid >> 6, lane = tid & 63;
  const int c = lane & 31, hh = lane >> 5;

  // balanced decode: CU gets L, L+256, L+512, L+768 -> {(p,h0),(p,h1),(15-p,h0),(15-p,h1)}
  const int L = blockIdx.x;
  const int group = L >> 8, r0_ = L & 255;
  const int pairid = r0_ & 7, bh = r0_ >> 3;
  const int qc = (group & 2) ? (15 - pairid) : pairid;
  const int half = group & 1;
  const int b = bh >> 4, h = bh & 15;
  const int q0w = qc * 128 + wave * 32;        // this wave's 32 q-rows

  const unsigned short* Qb = qkv + (size_t)b * S * LD + h * 64;
  const unsigned short* Kb = Qb + 1024;
  const unsigned short* Vt = VtG + (size_t)(b * 16 + h) * 64 * S;

  __shared__ __align__(16) unsigned short Ks[2][64 * 64];   // [kv][d], swizzled
  __shared__ __align__(16) unsigned short Vs[2][64 * 64];   // [d][kv], swizzled

  const int srow = lane >> 3;                        // 0..7
  const int srcg = ((lane & 7) ^ srow) << 3;         // pre-swizzled granule (shorts)
  const int wrow = wave * 8 + srow;                  // 0..31

  const int nit = qc + 1;          // KV tiles this block processes
  const int tb = half ? nit : 0;   // tile index base for this half

  // prologue: stage tile tb into buffer 0 (issued before Q loads)
  {
    const int cc = tb << 6;
    gload_lds16(Kb + (size_t)(cc + wrow) * LD + srcg,      Ks[0] + wave * 512);
    gload_lds16(Kb + (size_t)(cc + 32 + wrow) * LD + srcg, Ks[0] + 2048 + wave * 512);
    gload_lds16(Vt + (size_t)wrow * S + cc + srcg,         Vs[0] + wave * 512);
    gload_lds16(Vt + (size_t)(32 + wrow) * S + cc + srcg,  Vs[0] + 2048 + wave * 512);
  }

  // Q fragments: lane holds Q[q0w+c][kc*16 + hh*8 + 0..7]
  bf16x8 qf[4];
#pragma unroll
  for (int kc = 0; kc < 4; ++kc)
    qf[kc] = ldbf8(Qb + (size_t)(q0w + c) * LD + kc * 16 + hh * 8);

  f32x16 acc[2] = {};            // O^T: row d = db*32+(r&3)+8(r>>2)+4hh, col = q0w+c
  float m_r = -1e30f, l_r = 0.f; // m uniform across hh pair; l per-lane partial
  const float CE = 0.125f * 1.44269504f;  // 1/sqrt(dh) * log2(e)

  int cur = 0;
  const int swz = (c & 7) << 3;  // read-side XOR (shorts)

  for (int t = 0; t < nit; ++t) {
    if (t + 1 < nit) {           // issue next tile's loads; stay in flight
      const int c1 = (tb + t + 1) << 6;
      unsigned short* KsN = Ks[cur ^ 1];
      unsigned short* VsN = Vs[cur ^ 1];
      gload_lds16(Kb + (size_t)(c1 + wrow) * LD + srcg,      KsN + wave * 512);
      gload_lds16(Kb + (size_t)(c1 + 32 + wrow) * LD + srcg, KsN + 2048 + wave * 512);
      gload_lds16(Vt + (size_t)wrow * S + c1 + srcg,         VsN + wave * 512);
      gload_lds16(Vt + (size_t)(32 + wrow) * S + c1 + srcg,  VsN + 2048 + wave * 512);
      asm volatile("s_waitcnt vmcnt(4)" ::: "memory");   // tile t resident
    } else {
      asm volatile("s_waitcnt vmcnt(0)" ::: "memory");
    }
    __builtin_amdgcn_s_barrier();  // all waves' stage(t) visible

    const int c0 = (tb + t) << 6;
    const unsigned short* KsC = Ks[cur];
    const unsigned short* VsC = Vs[cur];

    if (c0 <= q0w + 31) {  // wave has unmasked rows in this tile
      int nv = ((q0w + 31 - c0) >> 5) + 1; if (nv > 2) nv = 2;  // valid 32-kv chunks

      // K fragments: A-operand rows kv = n*32+c, k = kc*16+hh*8
      bf16x8 kf[2][4];
#pragma unroll
      for (int n = 0; n < 2; ++n) if (n < nv)
#pragma unroll
        for (int kc = 0; kc < 4; ++kc)
          kf[n][kc] = ldbf8(KsC + (n * 32 + c) * 64 + ((kc * 16 + hh * 8) ^ swz));

      // S^T = K Q^T : st[n] rows kv, cols qrow
      f32x16 st[2] = {};
      __builtin_amdgcn_s_setprio(1);
#pragma unroll
      for (int n = 0; n < 2; ++n) if (n < nv)
#pragma unroll
        for (int kc = 0; kc < 4; ++kc)
          st[n] = __builtin_amdgcn_mfma_f32_32x32x16_bf16(kf[n][kc], qf[kc], st[n], 0, 0, 0);
      __builtin_amdgcn_s_setprio(0);

      // V fragments early (latency hides under softmax): rows d = db*32+c
      bf16x8 vf[2][4];
#pragma unroll
      for (int db = 0; db < 2; ++db)
#pragma unroll
        for (int kk = 0; kk < 4; ++kk) if (kk < 2 * nv)
          vf[db][kk] = ldbf8(VsC + (db * 32 + c) * 64 + ((kk * 16 + hh * 8) ^ swz));

      if (c0 + 63 > q0w) {  // causal mask (diag region only)
#pragma unroll
        for (int n = 0; n < 2; ++n) if (n < nv)
#pragma unroll
          for (int r = 0; r < 16; ++r) {
            const int kv = c0 + n * 32 + (r & 3) + 8 * (r >> 2) + 4 * hh;
            if (kv > q0w + c) st[n][r] = -1e30f;
          }
      }

      // defer-max online softmax; 4-partial trees break serial VALU chains
      f32x4 pm = {-1e30f, -1e30f, -1e30f, -1e30f};
#pragma unroll
      for (int n = 0; n < 2; ++n) if (n < nv)
#pragma unroll
        for (int r = 0; r < 16; ++r) pm[r & 3] = fmaxf(pm[r & 3], st[n][r]);
      const float pmax = fmaxf(fmaxf(pm[0], pm[1]), fmaxf(pm[2], pm[3]));
      if (!__all(pmax <= m_r + 64.f)) {   // rare: update running max, rescale
        float px = fmaxf(pmax, __shfl_xor(pmax, 32));
        const float mn = fmaxf(m_r, px);
        const float sf = __builtin_amdgcn_exp2f((m_r - mn) * CE);
        m_r = mn; l_r *= sf;
#pragma unroll
        for (int db = 0; db < 2; ++db) acc[db] *= sf;
      }
      const float mC = m_r * CE;
      f32x4 la = {0.f, 0.f, 0.f, 0.f};
#pragma unroll
      for (int n = 0; n < 2; ++n) if (n < nv)
#pragma unroll
        for (int r = 0; r < 16; ++r) {
          const float p = __builtin_amdgcn_exp2f(fmaf(st[n][r], CE, -mC));
          st[n][r] = p;
          la[r & 3] += p;
        }
      l_r += (la[0] + la[1]) + (la[2] + la[3]);

      // P relayout in-register: cvt_pk pairs then permlane32_swap
      bf16x8 pa[4];
#pragma unroll
      for (int n = 0; n < 2; ++n) if (n < nv) {
        unsigned T0 = cvtpk_bf16(st[n][0],  st[n][1]);
        unsigned T1 = cvtpk_bf16(st[n][2],  st[n][3]);
        unsigned T2 = cvtpk_bf16(st[n][4],  st[n][5]);
        unsigned T3 = cvtpk_bf16(st[n][6],  st[n][7]);
        unsigned T4 = cvtpk_bf16(st[n][8],  st[n][9]);
        unsigned T5 = cvtpk_bf16(st[n][10], st[n][11]);
        unsigned T6 = cvtpk_bf16(st[n][12], st[n][13]);
        unsigned T7 = cvtpk_bf16(st[n][14], st[n][15]);
        asm("v_permlane32_swap_b32 %0, %1" : "+v"(T0), "+v"(T2));
        asm("v_permlane32_swap_b32 %0, %1" : "+v"(T1), "+v"(T3));
        asm("v_permlane32_swap_b32 %0, %1" : "+v"(T4), "+v"(T6));
        asm("v_permlane32_swap_b32 %0, %1" : "+v"(T5), "+v"(T7));
        uint4v w0; w0[0] = T0; w0[1] = T1; w0[2] = T2; w0[3] = T3;
        uint4v w1; w1[0] = T4; w1[1] = T5; w1[2] = T6; w1[3] = T7;
        pa[2 * n]     = __builtin_bit_cast(bf16x8, w0);
        pa[2 * n + 1] = __builtin_bit_cast(bf16x8, w1);
      }

      // O^T += V^T P
      __builtin_amdgcn_s_setprio(1);
#pragma unroll
      for (int kk = 0; kk < 4; ++kk) if (kk < 2 * nv)
#pragma unroll
        for (int db = 0; db < 2; ++db)
          acc[db] = __builtin_amdgcn_mfma_f32_32x32x16_bf16(vf[db][kk], pa[kk], acc[db], 0, 0, 0);
      __builtin_amdgcn_s_setprio(0);
    }

    __builtin_amdgcn_s_barrier();  // all waves done reading buf[cur]
    cur ^= 1;
  }

  // epilogue: store normalized bf16 partial (avg) + per-row stats
  const float lt = l_r + __shfl_xor(l_r, 32);
  const float inv = lt > 0.f ? 1.f / lt : 0.f;   // guard fully-masked high waves
  unsigned short* Op = half ? OhP : OlP;
  const size_t rowbase = (size_t)(b * S + q0w + c) * H + h * 64;
#pragma unroll
  for (int db = 0; db < 2; ++db)
#pragma unroll
    for (int blk = 0; blk < 4; ++blk) {
      ushort4v o;
#pragma unroll
      for (int j = 0; j < 4; ++j) o[j] = f2bf(acc[db][blk * 4 + j] * inv);
      *(ushort4v*)(Op + rowbase + db * 32 + blk * 8 + hh * 4) = o;
    }
  if (hh == 0) {
    float* sp = stats + ((((size_t)(b * 16 + h)) << 11) + q0w + c) * 4 + (half ? 2 : 0);
    sp[0] = m_r; sp[1] = lt;
  }
}

// ---------------- merge the two KV-half partials ----------------
__global__ __launch_bounds__(256) void attn_merge_kernel(
    const unsigned short* __restrict__ Ol,   // low partial (avg), (B*S) x H
    const unsigned short* __restrict__ Oh,   // high partial (avg)
    const float* __restrict__ stats,         // [bh*2048+s][4] = ml,ll,mh,lh
    unsigned short* __restrict__ Oout) {     // final bf16, (B*S) x H
  const float CE = 0.125f * 1.44269504f;
  const int i = blockIdx.x * 256 + threadIdx.x;  // one ushort8 per thread
  const int r = i >> 7;                          // row in [0, 4096)
  const int g8 = i & 127;
  const int h = g8 >> 3;
  const int s = r & 2047, b = r >> 11;
  const float4v st = *(const float4v*)(stats + ((((size_t)(b * 16 + h)) << 11) + s) * 4);
  const float mn = fmaxf(st[0], st[2]);
  const float wl_ = st[1] * __builtin_amdgcn_exp2f((st[0] - mn) * CE);
  const float wh_ = st[3] * __builtin_amdgcn_exp2f((st[2] - mn) * CE);
  const float inv = 1.f / (wl_ + wh_);
  const float wl = wl_ * inv, wh = wh_ * inv;
  const size_t off = (size_t)i * 8;
  const ushort8 a = *(const ushort8*)(Ol + off);
  const ushort8 cc = *(const ushort8*)(Oh + off);
  ushort8 o;
#pragma unroll
  for (int j = 0; j < 8; ++j)
    o[j] = f2bf(wl * bf2f(a[j]) + wh * bf2f(cc[j]));
  *(ushort8*)(Oout + off) = o;
}

extern "C" void kernel_launch(void* const* d_in, const int* in_sizes, int n_in,
                              void* d_out, int out_size, void* d_ws, size_t ws_size,
                              hipStream_t stream) {
  const float* x     = (const float*)d_in[0];
  const float* w_qkv = (const float*)d_in[1];
  const float* w_out = (const float*)d_in[2];
  const int B = 2, S = 2048, H = 1024;
  const int M = B * S;  // 4096

  // workspace layout (ushort elements), total 48 MB:
  unsigned short* xb    = (unsigned short*)d_ws;        // M*H    (8 MB) -> OhP after QKV
  unsigned short* wqkvT = xb + (size_t)M * H;           // 3H*H   (6 MB) -> stats after QKV
  unsigned short* woutT = wqkvT + (size_t)3 * H * H;    // H*H    (2 MB)
  unsigned short* qkb   = woutT + (size_t)H * H;        // M*2048 (16 MB) : Q|K
  unsigned short* VtG   = qkb + (size_t)M * 2048;       // B*16*64*S (8 MB)
  unsigned short* Ob    = VtG + (size_t)B * 16 * 64 * S;// M*H    (8 MB) : low partial
  unsigned short* OhP   = xb;                           // reuse (exactly M*H)
  float*          stats = (float*)wqkvT;                // 1 MB of the 6 MB region

  // fused pre-pass: cvt(x) + transpose(w_qkv) + transpose(w_out)
  prepass_kernel<<<5120, 256, 0, stream>>>(x, w_qkv, w_out, xb, wqkvT, woutT);

  // qkv = x @ w_qkv; Q|K -> qkb (ldc=2048), V third -> VtG in (b,h,d,s) layout
  gemm_bt_kernel<true><<<dim3(M / 128, (3 * H) / 128), 256, 0, stream>>>(
      xb, wqkvT, qkb, M, 3 * H, H, H, H, 2048, VtG);

  // causal multi-head attention (1024 balanced KV-split blocks, 4 waves each)
  attn_kernel<<<1024, 256, 0, stream>>>(qkb, VtG, Ob, OhP, stats);

  // merge the two KV halves -> Ob
  attn_merge_kernel<<<2048, 256, 0, stream>>>(Ob, OhP, stats, Ob);

  // out = attn @ w_out (fp32 out, 64x128 tiles -> 512 blocks = 2 blocks/CU)
  gemm_bt64_kernel<<<dim3(M / 64, H / 128), 256, 0, stream>>>(
      Ob, woutT, (float*)d_out, H, H, H, H);
}